// Round 8
// baseline (2839.193 us; speedup 1.0000x reference)
//
#include <hip/hip_runtime.h>
#include <stdint.h>

#define NB 512
#define NH 512
#define NG 2048
#define NF 32
#define NSQ 64
#define NO 32

typedef unsigned short ushort_t;
typedef __attribute__((ext_vector_type(8))) short bf16x8;
typedef __attribute__((ext_vector_type(4))) unsigned int uiv4;
typedef __attribute__((ext_vector_type(16))) float f32x16;

__device__ __forceinline__ float sigf(float x){ return 1.f/(1.f+__expf(-x)); }
__device__ __forceinline__ float tanh_(float x){ return 1.f-2.f/(1.f+__expf(2.f*x)); }
__device__ __forceinline__ unsigned short f2bf(float f){
  uint32_t u=__float_as_uint(f); u=(u+0x7FFFu+((u>>16)&1u))>>16; return (unsigned short)u; }
__device__ __forceinline__ float bf2f(unsigned short u){ return __uint_as_float(((uint32_t)u)<<16); }
__device__ __forceinline__ float bf2f_s(short s){ return __uint_as_float(((uint32_t)(unsigned short)s)<<16); }

__device__ __forceinline__ bf16x8 vload16(const ushort_t* p){
  union { uiv4 u; bf16x8 b; } c; c.u = *(const uiv4*)p; return c.b;
}

// ---------------- zero (hA + flag words, 65792 float4 = 1MB + 4KB) ----------------
__global__ __launch_bounds__(256)
void zero_k(float4* __restrict__ p, int n) {
  int i = blockIdx.x * 256 + threadIdx.x;
  if (i < n) p[i] = make_float4(0.f, 0.f, 0.f, 0.f);
}

// ---------------- prep: Wh / Wh+Wd@Wx packed to per-block fragment panels ----
// Layout: [cb(32)][ss(32)][qh(2)][part(2)][lane(64)][e(8)] bf16 (65536 per cb).
// q = cb*64+qh*32+(lane&31); k = ss*16+(lane>>5)*8+e; col=(q&3)*NH+(q>>2).
__global__ __launch_bounds__(256)
void prep_w_k(const float* __restrict__ Wh, const float* __restrict__ Wd,
              const float* __restrict__ Wx,
              ushort_t* __restrict__ Wpk, ushort_t* __restrict__ Wppk)
{
  __shared__ float Wds[16][32];
  __shared__ float Wxs[32][65];
  const int bi = blockIdx.x;
  const int cb = bi >> 5, ss = bi & 31;
  const int k0 = ss * 16;
  const int tid = threadIdx.x;
  for (int i = tid; i < 512; i += 256) { int kl = i >> 5, o = i & 31; Wds[kl][o] = Wd[(size_t)(k0+kl)*NO + o]; }
  for (int i = tid; i < 2048; i += 256) {
    int o = i >> 6, ql = i & 63;
    int q = cb*64 + ql; int col = (q&3)*NH + (q>>2);
    Wxs[o][ql] = Wx[(size_t)o*NG + col];
  }
  __syncthreads();
  const int lane = tid & 63;
  const int part = (tid >> 6) & 1;
  const int qh   = tid >> 7;
  const int ql   = qh*32 + (lane & 31);
  const int q    = cb*64 + ql;
  const int col  = (q&3)*NH + (q>>2);
  const size_t obase = (size_t)cb*65536 + ((size_t)(ss*2 + qh)*2 + part)*512 + lane*8;
  ushort_t r1[8], r2[8];
  #pragma unroll
  for (int e = 0; e < 8; ++e) {
    int kl = (lane>>5)*8 + e;
    float v = Wh[(size_t)(k0+kl)*NG + col];
    float fo = 0.f;
    #pragma unroll
    for (int o = 0; o < 32; ++o) fo += Wds[kl][o] * Wxs[o][ql];
    float vp = v + fo;
    unsigned short h1 = f2bf(v), h2 = f2bf(vp);
    r1[e] = part ? f2bf(v  - bf2f(h1)) : h1;
    r2[e] = part ? f2bf(vp - bf2f(h2)) : h2;
  }
  *(uiv4*)&Wpk[obase]  = *(const uiv4*)r1;
  *(uiv4*)&Wppk[obase] = *(const uiv4*)r2;
}

// ---------------- prep: Wx panels [cb(32)][xs(2)][qh(2)][part(2)][lane][e] ----------------
__global__ __launch_bounds__(256)
void prep_wx_k(const float* __restrict__ Wx, ushort_t* __restrict__ Wxpk) {
  size_t i0 = ((size_t)blockIdx.x*256 + threadIdx.x) * 8;   // 131072 total, grid 64
  int lane = (int)((i0 >> 3) & 63);
  int part = (int)((i0 >> 9) & 1);
  int qh   = (int)((i0 >> 10) & 1);
  int xs   = (int)((i0 >> 11) & 1);
  int cb   = (int)(i0 >> 12);
  int q = cb*64 + qh*32 + (lane&31);
  int col = (q&3)*NH + (q>>2);
  int f0 = xs*16 + (lane>>5)*8;
  ushort_t r[8];
  #pragma unroll
  for (int e = 0; e < 8; ++e) {
    float v = Wx[(size_t)(f0+e)*NG + col];
    unsigned short h = f2bf(v);
    r[e] = part ? f2bf(v - bf2f(h)) : h;
  }
  *(uiv4*)&Wxpk[i0] = *(const uiv4*)r;
}

// ---------------- prep: x packed [t(64)][g(8)][wr(2)][xs(2)][part(2)][lane][e] ----------------
// total 2^21 elements -> grid 1024 x 256 thr x 8 elem
__global__ __launch_bounds__(256)
void prep_x_k(const float* __restrict__ x, ushort_t* __restrict__ xpk) {
  size_t i0 = ((size_t)blockIdx.x*256 + threadIdx.x) * 8;
  int lane = (int)((i0 >> 3) & 63);
  int part = (int)((i0 >> 9) & 1);
  int xs   = (int)((i0 >> 10) & 1);
  int wr   = (int)((i0 >> 11) & 1);
  int g    = (int)((i0 >> 12) & 7);
  int t    = (int)(i0 >> 15);
  int row = g*64 + wr*32 + (lane & 31);
  int f0 = xs*16 + (lane>>5)*8;
  const float* src = &x[((size_t)row*NSQ + t)*NF + f0];
  ushort_t r[8];
  #pragma unroll
  for (int e = 0; e < 8; ++e) {
    float v = src[e];
    unsigned short h = f2bf(v);
    r[e] = part ? f2bf(v - bf2f(h)) : h;
  }
  *(uiv4*)&xpk[i0] = *(const uiv4*)r;
}

// ---------------- prep: permuted biases ----------------
__global__ __launch_bounds__(256)
void prep_bias_k(const float* __restrict__ b, const float* __restrict__ bd,
                 const float* __restrict__ Wx, float* __restrict__ b_p,
                 float* __restrict__ bp_p) {
  int q = blockIdx.x * 256 + threadIdx.x;
  int gcol = (q & 3) * NH + (q >> 2);
  float v = b[gcol];
  float f = v;
  #pragma unroll
  for (int o = 0; o < 32; ++o) f += bd[o] * Wx[(size_t)o * NG + gcol];
  b_p[q] = v; bp_p[q] = f;
}

// ---------------- prep: WdT[o][k] ----------------
__global__ __launch_bounds__(256)
void prep_wd_k(const float* __restrict__ Wd, float* __restrict__ WdT) {
  int i = blockIdx.x*256 + threadIdx.x;   // 16384, grid 64
  int o = i >> 9, k = i & 511;
  WdT[i] = Wd[(size_t)k*NO + o];
}

// ---------------- group barrier: flag vector + ACQUIRE fence ----------------
// Release side (caller): h stored with write-through sc0|sc1 + vmcnt(0) drain,
// then own flag stamped (sc0|sc1). Acquire side: poll the 32 flags with
// coherent loads; once all arrived, one agent-scope acquire fence
// (-> buffer_inv sc1: invalidates this XCD's clean L1/L2 lines) so the
// SUBSEQUENT NORMAL cached loads of h see the new step's data. This restores
// L2 aggregation for the 32 MB/step h reads (the R7 bottleneck: sc1-bypass
// reads ran at ~1.5 TB/s) with no XCD-placement assumption.
__device__ __forceinline__ void gridbar(unsigned* gflags, int cb, unsigned target,
                                        int wv, int lane) {
  asm volatile("s_waitcnt vmcnt(0)" ::: "memory");   // h stores at coherence point
  __syncthreads();
  if (wv == 0) {
    if (lane == 0) {
      asm volatile("global_store_dword %0, %1, off sc0 sc1"
                   :: "v"(gflags + cb), "v"(target) : "memory");
    }
    const unsigned* fp = gflags + (lane & 31);
    unsigned f;
    for (;;) {
      asm volatile("global_load_dword %0, %1, off sc0 sc1"
                   : "=v"(f) : "v"(fp) : "memory");
      asm volatile("s_waitcnt vmcnt(0)" ::: "memory");
      if (__all((int)(f >= target))) break;
      __builtin_amdgcn_s_sleep(2);
    }
    __builtin_amdgcn_fence(__ATOMIC_ACQUIRE, "agent");  // inv L1 + XCD L2
  }
  __syncthreads();
}

// ---------------- one LSTM step (device) ----------------
template<bool WARM>
__device__ __forceinline__ void lstm_step(
    const ushort_t* __restrict__ hin, ushort_t* __restrict__ hout,
    const bf16x8 (&bh0)[8], const bf16x8 (&bl0)[8],
    const bf16x8 (&bh1)[8], const bf16x8 (&bl1)[8],
    const ushort_t* __restrict__ wxp,
    const ushort_t* __restrict__ xp,
    float (*Zs)[68], const float* wdcol, float (*red)[64], const float* bias_s,
    float2& creg,
    int tid, int lane, int wr, int kq, int g, int cb,
    size_t Ab, size_t hwbase,
    float* __restrict__ out, int s_out, float bdc)
{
  f32x16 acc0, acc1;
  #pragma unroll
  for (int i = 0; i < 16; ++i) { acc0[i] = 0.f; acc1[i] = 0.f; }

  // ---- A loads: NORMAL cached loads (L1/L2); freshness guaranteed by the
  // acquire fence in the preceding gridbar. Mostly L2 hits (panel shared by
  // all same-group blocks on this XCD).
  const ushort_t* A0 = hin + Ab;
  bf16x8 vh[8], vl[8];
  #pragma unroll
  for (int s = 0; s < 8; ++s) {
    vh[s] = vload16(A0 + (size_t)s*1024);
    vl[s] = vload16(A0 + (size_t)s*1024 + 512);
  }

  float pacc = 0.f;
  const int kwb = kq*128 + (lane>>5)*8;

  #pragma unroll
  for (int s = 0; s < 8; ++s) {
    const bf16x8 a_h = vh[s];
    const bf16x8 a_l = vl[s];
    acc0 = __builtin_amdgcn_mfma_f32_32x32x16_bf16(a_h, bh0[s], acc0, 0,0,0);
    acc1 = __builtin_amdgcn_mfma_f32_32x32x16_bf16(a_h, bh1[s], acc1, 0,0,0);
    acc0 = __builtin_amdgcn_mfma_f32_32x32x16_bf16(a_h, bl0[s], acc0, 0,0,0);
    acc1 = __builtin_amdgcn_mfma_f32_32x32x16_bf16(a_h, bl1[s], acc1, 0,0,0);
    acc0 = __builtin_amdgcn_mfma_f32_32x32x16_bf16(a_l, bh0[s], acc0, 0,0,0);
    acc1 = __builtin_amdgcn_mfma_f32_32x32x16_bf16(a_l, bh1[s], acc1, 0,0,0);
    if (!WARM) {
      float4 w0 = *(const float4*)&wdcol[kwb + s*16];
      float4 w1 = *(const float4*)&wdcol[kwb + s*16 + 4];
      pacc += (bf2f_s(a_h[0])+bf2f_s(a_l[0]))*w0.x + (bf2f_s(a_h[1])+bf2f_s(a_l[1]))*w0.y
            + (bf2f_s(a_h[2])+bf2f_s(a_l[2]))*w0.z + (bf2f_s(a_h[3])+bf2f_s(a_l[3]))*w0.w;
      pacc += (bf2f_s(a_h[4])+bf2f_s(a_l[4]))*w1.x + (bf2f_s(a_h[5])+bf2f_s(a_l[5]))*w1.y
            + (bf2f_s(a_h[6])+bf2f_s(a_l[6]))*w1.z + (bf2f_s(a_h[7])+bf2f_s(a_l[7]))*w1.w;
    }
  }

  // ---- x contribution (warmup, waves kq=1,3) ----
  if (WARM && (kq & 1)) {
    bf16x8 axh  = vload16(xp);         bf16x8 axl  = vload16(xp + 512);
    bf16x8 wxh0 = vload16(wxp);        bf16x8 wxl0 = vload16(wxp + 512);
    bf16x8 wxh1 = vload16(wxp + 1024); bf16x8 wxl1 = vload16(wxp + 1536);
    acc0 = __builtin_amdgcn_mfma_f32_32x32x16_bf16(axh, wxh0, acc0, 0,0,0);
    acc1 = __builtin_amdgcn_mfma_f32_32x32x16_bf16(axh, wxh1, acc1, 0,0,0);
    acc0 = __builtin_amdgcn_mfma_f32_32x32x16_bf16(axh, wxl0, acc0, 0,0,0);
    acc1 = __builtin_amdgcn_mfma_f32_32x32x16_bf16(axh, wxl1, acc1, 0,0,0);
    acc0 = __builtin_amdgcn_mfma_f32_32x32x16_bf16(axl, wxh0, acc0, 0,0,0);
    acc1 = __builtin_amdgcn_mfma_f32_32x32x16_bf16(axl, wxh1, acc1, 0,0,0);
  }

  if (!WARM) {
    pacc += __shfl_xor(pacc, 32);
    if (lane < 32) red[kq][wr*32 + lane] = pacc;
  }

  // ---- K-split merge through LDS ----
  const int qb = lane & 31;
  if (kq == 0) {
    #pragma unroll
    for (int r = 0; r < 16; ++r) {
      int row = wr*32 + (r&3) + 8*(r>>2) + 4*(lane>>5);
      Zs[row][qb] = acc0[r];
      Zs[row][32 + qb] = acc1[r];
    }
  }
  __syncthreads();
  if (kq != 0) {
    #pragma unroll
    for (int r = 0; r < 16; ++r) {
      int row = wr*32 + (r&3) + 8*(r>>2) + 4*(lane>>5);
      atomicAdd(&Zs[row][qb], acc0[r]);
      atomicAdd(&Zs[row][32 + qb], acc1[r]);
    }
  }
  __syncthreads();

  // ---- gates + c/h update; h stored write-through coherent (sc0 sc1) ----
  {
    const int grow = tid >> 3;
    const int jq = tid & 7;
    float4 z0 = *(const float4*)&Zs[grow][jq*8];
    float4 z1 = *(const float4*)&Zs[grow][jq*8 + 4];
    float4 bvA = *(const float4*)&bias_s[jq*8];
    float4 bvB = *(const float4*)&bias_s[jq*8 + 4];
    float zi0 = z0.x + bvA.x, zf0 = z0.y + bvA.y, zg0 = z0.z + bvA.z, zo0 = z0.w + bvA.w;
    float zi1 = z1.x + bvB.x, zf1 = z1.y + bvB.y, zg1 = z1.z + bvB.z, zo1 = z1.w + bvB.w;
    float c0 = sigf(zf0)*creg.x + sigf(zi0)*tanh_(zg0);
    float c1 = sigf(zf1)*creg.y + sigf(zi1)*tanh_(zg1);
    creg.x = c0; creg.y = c1;
    float h0 = sigf(zo0)*tanh_(c0);
    float h1 = sigf(zo1)*tanh_(c1);
    unsigned short hh0 = f2bf(h0), hh1 = f2bf(h1);
    unsigned short hl0 = f2bf(h0 - bf2f(hh0)), hl1 = f2bf(h1 - bf2f(hh1));
    unsigned hip = (unsigned)hh0 | ((unsigned)hh1 << 16);
    unsigned lop = (unsigned)hl0 | ((unsigned)hl1 << 16);
    asm volatile("global_store_dword %0, %1, off sc0 sc1"
                 :: "v"(hout + hwbase), "v"(hip) : "memory");
    asm volatile("global_store_dword %0, %1, off sc0 sc1"
                 :: "v"(hout + hwbase + 512), "v"(lop) : "memory");
  }

  if (!WARM && tid < 64) {
    float sum = red[0][tid] + red[1][tid] + red[2][tid] + red[3][tid] + bdc;
    out[((size_t)(g*64 + tid)*NSQ + s_out)*NO + cb] = sum;
  }
}

// ---------------- persistent fused LSTM ----------------
// Grid 256 (8 row-groups x 32 col-blocks), 512 thr = 8 waves (wr row-half,
// kq K-quarter). Weights register-resident; c in 2 regs; h release/acquire:
// sc0|sc1 write-through stores + flag barrier + agent acquire fence + normal
// cached reads. No XCD-placement assumption. One dispatch.
__global__ __launch_bounds__(512, 2)
void lstm_persist_k(ushort_t* __restrict__ hA, ushort_t* __restrict__ hB,
                    const ushort_t* __restrict__ Wpk, const ushort_t* __restrict__ Wppk,
                    const ushort_t* __restrict__ Wxpk, const ushort_t* __restrict__ xpk,
                    const float* __restrict__ b_p, const float* __restrict__ bp_p,
                    const float* __restrict__ WdT, const float* __restrict__ bd,
                    unsigned* __restrict__ flags, float* __restrict__ out)
{
  __shared__ float Zs[64][68];
  __shared__ float wdcol[512];
  __shared__ float red[4][64];
  __shared__ float bias_s[64];

  const int tid = threadIdx.x;
  const int lane = tid & 63;
  const int wv = tid >> 6;
  const int wr = wv & 1, kq = wv >> 1;
  const int g  = (int)blockIdx.x & 7;
  const int cb = (int)blockIdx.x >> 3;

  unsigned* gflags = flags + g*32;

  const int grow = tid >> 3;
  const int jq = tid & 7;
  const int lane_w = (grow & 31) + 32*(jq >> 2);
  const int e0 = (jq*2) & 7;
  const size_t hwbase = (((size_t)(g*2 + (grow>>5))*32 + cb)*2)*512 + lane_w*8 + e0;
  const size_t Ab = (((size_t)(g*2 + wr)*32 + kq*8)*2)*512 + lane*8;

  // persistent weight panel (warmup set)
  bf16x8 bh0[8], bl0[8], bh1[8], bl1[8];
  {
    const ushort_t* Wsec = Wpk + (size_t)cb*65536;
    #pragma unroll
    for (int s = 0; s < 8; ++s) {
      const ushort_t* p = Wsec + (size_t)(kq*8+s)*2048 + lane*8;
      bh0[s] = vload16(p);        bl0[s] = vload16(p + 512);
      bh1[s] = vload16(p + 1024); bl1[s] = vload16(p + 1536);
    }
  }
  const ushort_t* wxp = Wxpk + (size_t)(cb*2 + (kq>>1))*2048 + lane*8;

  wdcol[tid] = WdT[(size_t)cb*512 + tid];
  if (tid < 64) bias_s[tid] = b_p[cb*64 + tid];
  const float bdc = bd[cb];
  float2 creg = make_float2(0.f, 0.f);
  __syncthreads();

  // ---- warmup: 64 steps with x ----
  for (int t = 0; t < 64; ++t) {
    const ushort_t* hin = (t & 1) ? hB : hA;
    ushort_t* hout = (t & 1) ? hA : hB;
    const ushort_t* xp = xpk + ((((size_t)t*8 + g)*2 + wr)*2 + (kq>>1))*1024 + lane*8;
    lstm_step<true>(hin, hout, bh0, bl0, bh1, bl1, wxp, xp,
                    Zs, wdcol, red, bias_s, creg,
                    tid, lane, wr, kq, g, cb, Ab, hwbase, out, 0, bdc);
    gridbar(gflags, cb, (unsigned)(t+1), wv, lane);
  }

  // ---- switch to folded decode weights + folded bias ----
  {
    const ushort_t* Wsec = Wppk + (size_t)cb*65536;
    #pragma unroll
    for (int s = 0; s < 8; ++s) {
      const ushort_t* p = Wsec + (size_t)(kq*8+s)*2048 + lane*8;
      bh0[s] = vload16(p);        bl0[s] = vload16(p + 512);
      bh1[s] = vload16(p + 1024); bl1[s] = vload16(p + 1536);
    }
  }
  if (tid < 64) bias_s[tid] = bp_p[cb*64 + tid];
  __syncthreads();

  // ---- decode: 63 steps, step st emits pred_{st-64} from h_in ----
  for (int st = 64; st < 127; ++st) {
    const ushort_t* hin = (st & 1) ? hB : hA;
    ushort_t* hout = (st & 1) ? hA : hB;
    lstm_step<false>(hin, hout, bh0, bl0, bh1, bl1, wxp, hin /*unused*/,
                     Zs, wdcol, red, bias_s, creg,
                     tid, lane, wr, kq, g, cb, Ab, hwbase, out, st - 64, bdc);
    gridbar(gflags, cb, (unsigned)(st+1), wv, lane);
  }

  // ---- final pred_63 from h'_63 (in hB; fresh after last gridbar fence) ----
  {
    const ushort_t* A0 = hB + Ab;
    const int kwb = kq*128 + (lane>>5)*8;
    float pacc = 0.f;
    #pragma unroll
    for (int s = 0; s < 8; ++s) {
      const bf16x8 a_h = vload16(A0 + (size_t)s*1024);
      const bf16x8 a_l = vload16(A0 + (size_t)s*1024 + 512);
      float4 w0 = *(const float4*)&wdcol[kwb + s*16];
      float4 w1 = *(const float4*)&wdcol[kwb + s*16 + 4];
      pacc += (bf2f_s(a_h[0])+bf2f_s(a_l[0]))*w0.x + (bf2f_s(a_h[1])+bf2f_s(a_l[1]))*w0.y
            + (bf2f_s(a_h[2])+bf2f_s(a_l[2]))*w0.z + (bf2f_s(a_h[3])+bf2f_s(a_l[3]))*w0.w;
      pacc += (bf2f_s(a_h[4])+bf2f_s(a_l[4]))*w1.x + (bf2f_s(a_h[5])+bf2f_s(a_l[5]))*w1.y
            + (bf2f_s(a_h[6])+bf2f_s(a_l[6]))*w1.z + (bf2f_s(a_h[7])+bf2f_s(a_l[7]))*w1.w;
    }
    pacc += __shfl_xor(pacc, 32);
    if (lane < 32) red[kq][wr*32 + lane] = pacc;
    __syncthreads();
    if (tid < 64) {
      float sum = red[0][tid] + red[1][tid] + red[2][tid] + red[3][tid] + bdc;
      out[((size_t)(g*64 + tid)*NSQ + 63)*NO + cb] = sum;
    }
  }
}

extern "C" void kernel_launch(void* const* d_in, const int* in_sizes, int n_in,
                              void* d_out, int out_size, void* d_ws, size_t ws_size,
                              hipStream_t stream) {
  (void)in_sizes; (void)n_in; (void)out_size; (void)ws_size;
  const float* x  = (const float*)d_in[0];   // (512, 64, 32)
  const float* Wx = (const float*)d_in[1];   // (32, 2048)
  const float* Wh = (const float*)d_in[2];   // (512, 2048)
  const float* b  = (const float*)d_in[3];   // (2048,)
  const float* Wd = (const float*)d_in[4];   // (512, 32)
  const float* bd = (const float*)d_in[5];   // (32,)
  float* out = (float*)d_out;                // (512, 64, 32)

  // ws layout, ~15.0 MB total
  char* w = (char*)d_ws;
  ushort_t* hA    = (ushort_t*)(w + 0);            // 1 MB  (zeroed)
  unsigned* flags = (unsigned*)(w + 1048576);      // 1 KB  (zeroed; 8 groups x 32)
  ushort_t* hB    = (ushort_t*)(w + 1052672);      // 1 MB
  ushort_t* Wpk   = (ushort_t*)(w + 2101248);      // 4 MB
  ushort_t* Wppk  = (ushort_t*)(w + 6295552);      // 4 MB
  ushort_t* Wxpk  = (ushort_t*)(w + 10489856);     // 256 KB
  ushort_t* xpk   = (ushort_t*)(w + 10752000);     // 4 MB
  float* b_p  = (float*)(w + 14946304);            // 8 KB
  float* bp_p = (float*)(w + 14954496);            // 8 KB
  float* WdT  = (float*)(w + 14962688);            // 64 KB

  zero_k<<<257, 256, 0, stream>>>((float4*)w, 65792);   // hA + flags
  prep_w_k<<<1024, 256, 0, stream>>>(Wh, Wd, Wx, Wpk, Wppk);
  prep_wx_k<<<64, 256, 0, stream>>>(Wx, Wxpk);
  prep_x_k<<<1024, 256, 0, stream>>>(x, xpk);
  prep_bias_k<<<8, 256, 0, stream>>>(b, bd, Wx, b_p, bp_p);
  prep_wd_k<<<64, 256, 0, stream>>>(Wd, WdT);

  lstm_persist_k<<<256, 512, 0, stream>>>(hA, hB, Wpk, Wppk, Wxpk, xpk,
                                          b_p, bp_p, WdT, bd, flags, out);
}

// Round 9
// 2604.872 us; speedup vs baseline: 1.0900x; 1.0900x over previous
//
#include <hip/hip_runtime.h>
#include <stdint.h>

#define NB 512
#define NH 512
#define NG 2048
#define NF 32
#define NSQ 64
#define NO 32

typedef unsigned short ushort_t;
typedef __attribute__((ext_vector_type(8))) short bf16x8;
typedef __attribute__((ext_vector_type(4))) unsigned int uiv4;
typedef __attribute__((ext_vector_type(16))) float f32x16;

__device__ __forceinline__ float sigf(float x){ return 1.f/(1.f+__expf(-x)); }
__device__ __forceinline__ float tanh_(float x){ return 1.f-2.f/(1.f+__expf(2.f*x)); }
__device__ __forceinline__ unsigned short f2bf(float f){
  uint32_t u=__float_as_uint(f); u=(u+0x7FFFu+((u>>16)&1u))>>16; return (unsigned short)u; }
__device__ __forceinline__ float bf2f(unsigned short u){ return __uint_as_float(((uint32_t)u)<<16); }
__device__ __forceinline__ float bf2f_s(short s){ return __uint_as_float(((uint32_t)(unsigned short)s)<<16); }

__device__ __forceinline__ bf16x8 vload16(const ushort_t* p){
  union { uiv4 u; bf16x8 b; } c; c.u = *(const uiv4*)p; return c.b;
}
__device__ __forceinline__ bf16x8 as_bf(uiv4 v){
  union { uiv4 u; bf16x8 b; } c; c.u = v; return c.b;
}

// ---------------- zero (hA + flags/cnt region, 65792 float4 = 1MB + 4KB) ----------------
__global__ __launch_bounds__(256)
void zero_k(float4* __restrict__ p, int n) {
  int i = blockIdx.x * 256 + threadIdx.x;
  if (i < n) p[i] = make_float4(0.f, 0.f, 0.f, 0.f);
}

// ---------------- prep: Wh / Wh+Wd@Wx packed to per-block fragment panels ----
// Layout: [cb(32)][ss(32)][qh(2)][part(2)][lane(64)][e(8)] bf16 (65536 per cb).
// q = cb*64+qh*32+(lane&31); k = ss*16+(lane>>5)*8+e; col=(q&3)*NH+(q>>2).
__global__ __launch_bounds__(256)
void prep_w_k(const float* __restrict__ Wh, const float* __restrict__ Wd,
              const float* __restrict__ Wx,
              ushort_t* __restrict__ Wpk, ushort_t* __restrict__ Wppk)
{
  __shared__ float Wds[16][32];
  __shared__ float Wxs[32][65];
  const int bi = blockIdx.x;
  const int cb = bi >> 5, ss = bi & 31;
  const int k0 = ss * 16;
  const int tid = threadIdx.x;
  for (int i = tid; i < 512; i += 256) { int kl = i >> 5, o = i & 31; Wds[kl][o] = Wd[(size_t)(k0+kl)*NO + o]; }
  for (int i = tid; i < 2048; i += 256) {
    int o = i >> 6, ql = i & 63;
    int q = cb*64 + ql; int col = (q&3)*NH + (q>>2);
    Wxs[o][ql] = Wx[(size_t)o*NG + col];
  }
  __syncthreads();
  const int lane = tid & 63;
  const int part = (tid >> 6) & 1;
  const int qh   = tid >> 7;
  const int ql   = qh*32 + (lane & 31);
  const int q    = cb*64 + ql;
  const int col  = (q&3)*NH + (q>>2);
  const size_t obase = (size_t)cb*65536 + ((size_t)(ss*2 + qh)*2 + part)*512 + lane*8;
  ushort_t r1[8], r2[8];
  #pragma unroll
  for (int e = 0; e < 8; ++e) {
    int kl = (lane>>5)*8 + e;
    float v = Wh[(size_t)(k0+kl)*NG + col];
    float fo = 0.f;
    #pragma unroll
    for (int o = 0; o < 32; ++o) fo += Wds[kl][o] * Wxs[o][ql];
    float vp = v + fo;
    unsigned short h1 = f2bf(v), h2 = f2bf(vp);
    r1[e] = part ? f2bf(v  - bf2f(h1)) : h1;
    r2[e] = part ? f2bf(vp - bf2f(h2)) : h2;
  }
  *(uiv4*)&Wpk[obase]  = *(const uiv4*)r1;
  *(uiv4*)&Wppk[obase] = *(const uiv4*)r2;
}

// ---------------- prep: Wx panels [cb(32)][xs(2)][qh(2)][part(2)][lane][e] ----------------
__global__ __launch_bounds__(256)
void prep_wx_k(const float* __restrict__ Wx, ushort_t* __restrict__ Wxpk) {
  size_t i0 = ((size_t)blockIdx.x*256 + threadIdx.x) * 8;   // 131072 total, grid 64
  int lane = (int)((i0 >> 3) & 63);
  int part = (int)((i0 >> 9) & 1);
  int qh   = (int)((i0 >> 10) & 1);
  int xs   = (int)((i0 >> 11) & 1);
  int cb   = (int)(i0 >> 12);
  int q = cb*64 + qh*32 + (lane&31);
  int col = (q&3)*NH + (q>>2);
  int f0 = xs*16 + (lane>>5)*8;
  ushort_t r[8];
  #pragma unroll
  for (int e = 0; e < 8; ++e) {
    float v = Wx[(size_t)(f0+e)*NG + col];
    unsigned short h = f2bf(v);
    r[e] = part ? f2bf(v - bf2f(h)) : h;
  }
  *(uiv4*)&Wxpk[i0] = *(const uiv4*)r;
}

// ---------------- prep: x packed [t(64)][g(8)][wr(2)][xs(2)][part(2)][lane][e] ----------------
// total 2^21 elements -> grid 1024 x 256 thr x 8 elem
__global__ __launch_bounds__(256)
void prep_x_k(const float* __restrict__ x, ushort_t* __restrict__ xpk) {
  size_t i0 = ((size_t)blockIdx.x*256 + threadIdx.x) * 8;
  int lane = (int)((i0 >> 3) & 63);
  int part = (int)((i0 >> 9) & 1);
  int xs   = (int)((i0 >> 10) & 1);
  int wr   = (int)((i0 >> 11) & 1);
  int g    = (int)((i0 >> 12) & 7);
  int t    = (int)(i0 >> 15);
  int row = g*64 + wr*32 + (lane & 31);
  int f0 = xs*16 + (lane>>5)*8;
  const float* src = &x[((size_t)row*NSQ + t)*NF + f0];
  ushort_t r[8];
  #pragma unroll
  for (int e = 0; e < 8; ++e) {
    float v = src[e];
    unsigned short h = f2bf(v);
    r[e] = part ? f2bf(v - bf2f(h)) : h;
  }
  *(uiv4*)&xpk[i0] = *(const uiv4*)r;
}

// ---------------- prep: permuted biases ----------------
__global__ __launch_bounds__(256)
void prep_bias_k(const float* __restrict__ b, const float* __restrict__ bd,
                 const float* __restrict__ Wx, float* __restrict__ b_p,
                 float* __restrict__ bp_p) {
  int q = blockIdx.x * 256 + threadIdx.x;
  int gcol = (q & 3) * NH + (q >> 2);
  float v = b[gcol];
  float f = v;
  #pragma unroll
  for (int o = 0; o < 32; ++o) f += bd[o] * Wx[(size_t)o * NG + gcol];
  b_p[q] = v; bp_p[q] = f;
}

// ---------------- prep: WdT[o][k] ----------------
__global__ __launch_bounds__(256)
void prep_wd_k(const float* __restrict__ Wd, float* __restrict__ WdT) {
  int i = blockIdx.x*256 + threadIdx.x;   // 16384, grid 64
  int o = i >> 9, k = i & 511;
  WdT[i] = Wd[(size_t)k*NO + o];
}

// ---------------- group barrier: per-block flag vector (R7 mechanism) ----------
__device__ __forceinline__ void gridbar(unsigned* gflags, int cb, unsigned target,
                                        int wv, int lane) {
  asm volatile("s_waitcnt vmcnt(0)" ::: "memory");   // h stores complete (L2 or MALL)
  __syncthreads();
  if (wv == 0) {
    if (lane == 0) {
      asm volatile("global_store_dword %0, %1, off sc0 sc1"
                   :: "v"(gflags + cb), "v"(target) : "memory");
    }
    const unsigned* fp = gflags + (lane & 31);
    unsigned f;
    for (;;) {
      asm volatile("global_load_dword %0, %1, off sc0 sc1"
                   : "=v"(f) : "v"(fp) : "memory");
      asm volatile("s_waitcnt vmcnt(0)" ::: "memory");
      if (__all((int)(f >= target))) break;
      __builtin_amdgcn_s_sleep(2);
    }
  }
  __syncthreads();
}

// ---------------- one LSTM step (device) ----------------
// fast==1: group == physical XCD (runtime-verified). h loads sc0-only (L1
// bypass, served by the XCD-local L2 where the group's plain stores live).
// fast==0: exact R7 coherent path (sc0|sc1 bypass loads + write-through stores).
template<bool WARM>
__device__ __forceinline__ void lstm_step(
    const ushort_t* __restrict__ hin, ushort_t* __restrict__ hout,
    const bf16x8 (&bh0)[8], const bf16x8 (&bl0)[8],
    const bf16x8 (&bh1)[8], const bf16x8 (&bl1)[8],
    const ushort_t* __restrict__ wxp,
    const ushort_t* __restrict__ xp,
    float (*Zs)[68], const float* wdcol, float (*red)[64], const float* bias_s,
    float2& creg, int fast,
    int tid, int lane, int wr, int kq, int g, int cb,
    size_t Ab, size_t hwbase,
    float* __restrict__ out, int s_out, float bdc)
{
  f32x16 acc0, acc1;
  #pragma unroll
  for (int i = 0; i < 16; ++i) { acc0[i] = 0.f; acc1[i] = 0.f; }

  const ushort_t* A0 = hin + Ab;
  uiv4 vh[8], vl[8];
  if (fast) {
    #pragma unroll
    for (int s = 0; s < 8; ++s) {
      asm volatile("global_load_dwordx4 %0, %1, off sc0"
                   : "=v"(vh[s]) : "v"(A0 + (size_t)s*1024) : "memory");
      asm volatile("global_load_dwordx4 %0, %1, off sc0"
                   : "=v"(vl[s]) : "v"(A0 + (size_t)s*1024 + 512) : "memory");
    }
  } else {
    #pragma unroll
    for (int s = 0; s < 8; ++s) {
      asm volatile("global_load_dwordx4 %0, %1, off sc0 sc1"
                   : "=v"(vh[s]) : "v"(A0 + (size_t)s*1024) : "memory");
      asm volatile("global_load_dwordx4 %0, %1, off sc0 sc1"
                   : "=v"(vl[s]) : "v"(A0 + (size_t)s*1024 + 512) : "memory");
    }
  }
  asm volatile("s_waitcnt vmcnt(0)" ::: "memory");
  __builtin_amdgcn_sched_barrier(0);   // rule #18: keep MFMAs below the wait

  float pacc = 0.f;
  const int kwb = kq*128 + (lane>>5)*8;

  #pragma unroll
  for (int s = 0; s < 8; ++s) {
    const bf16x8 a_h = as_bf(vh[s]);
    const bf16x8 a_l = as_bf(vl[s]);
    acc0 = __builtin_amdgcn_mfma_f32_32x32x16_bf16(a_h, bh0[s], acc0, 0,0,0);
    acc1 = __builtin_amdgcn_mfma_f32_32x32x16_bf16(a_h, bh1[s], acc1, 0,0,0);
    acc0 = __builtin_amdgcn_mfma_f32_32x32x16_bf16(a_h, bl0[s], acc0, 0,0,0);
    acc1 = __builtin_amdgcn_mfma_f32_32x32x16_bf16(a_h, bl1[s], acc1, 0,0,0);
    acc0 = __builtin_amdgcn_mfma_f32_32x32x16_bf16(a_l, bh0[s], acc0, 0,0,0);
    acc1 = __builtin_amdgcn_mfma_f32_32x32x16_bf16(a_l, bh1[s], acc1, 0,0,0);
    if (!WARM) {
      float4 w0 = *(const float4*)&wdcol[kwb + s*16];
      float4 w1 = *(const float4*)&wdcol[kwb + s*16 + 4];
      pacc += (bf2f_s(a_h[0])+bf2f_s(a_l[0]))*w0.x + (bf2f_s(a_h[1])+bf2f_s(a_l[1]))*w0.y
            + (bf2f_s(a_h[2])+bf2f_s(a_l[2]))*w0.z + (bf2f_s(a_h[3])+bf2f_s(a_l[3]))*w0.w;
      pacc += (bf2f_s(a_h[4])+bf2f_s(a_l[4]))*w1.x + (bf2f_s(a_h[5])+bf2f_s(a_l[5]))*w1.y
            + (bf2f_s(a_h[6])+bf2f_s(a_l[6]))*w1.z + (bf2f_s(a_h[7])+bf2f_s(a_l[7]))*w1.w;
    }
  }

  // ---- x contribution (warmup, waves kq=1,3) ----
  if (WARM && (kq & 1)) {
    bf16x8 axh  = vload16(xp);         bf16x8 axl  = vload16(xp + 512);
    bf16x8 wxh0 = vload16(wxp);        bf16x8 wxl0 = vload16(wxp + 512);
    bf16x8 wxh1 = vload16(wxp + 1024); bf16x8 wxl1 = vload16(wxp + 1536);
    acc0 = __builtin_amdgcn_mfma_f32_32x32x16_bf16(axh, wxh0, acc0, 0,0,0);
    acc1 = __builtin_amdgcn_mfma_f32_32x32x16_bf16(axh, wxh1, acc1, 0,0,0);
    acc0 = __builtin_amdgcn_mfma_f32_32x32x16_bf16(axh, wxl0, acc0, 0,0,0);
    acc1 = __builtin_amdgcn_mfma_f32_32x32x16_bf16(axh, wxl1, acc1, 0,0,0);
    acc0 = __builtin_amdgcn_mfma_f32_32x32x16_bf16(axl, wxh0, acc0, 0,0,0);
    acc1 = __builtin_amdgcn_mfma_f32_32x32x16_bf16(axl, wxh1, acc1, 0,0,0);
  }

  if (!WARM) {
    pacc += __shfl_xor(pacc, 32);
    if (lane < 32) red[kq][wr*32 + lane] = pacc;
  }

  // ---- K-split merge through LDS ----
  const int qb = lane & 31;
  if (kq == 0) {
    #pragma unroll
    for (int r = 0; r < 16; ++r) {
      int row = wr*32 + (r&3) + 8*(r>>2) + 4*(lane>>5);
      Zs[row][qb] = acc0[r];
      Zs[row][32 + qb] = acc1[r];
    }
  }
  __syncthreads();
  if (kq != 0) {
    #pragma unroll
    for (int r = 0; r < 16; ++r) {
      int row = wr*32 + (r&3) + 8*(r>>2) + 4*(lane>>5);
      atomicAdd(&Zs[row][qb], acc0[r]);
      atomicAdd(&Zs[row][32 + qb], acc1[r]);
    }
  }
  __syncthreads();

  // ---- gates + c/h update ----
  {
    const int grow = tid >> 3;
    const int jq = tid & 7;
    float4 z0 = *(const float4*)&Zs[grow][jq*8];
    float4 z1 = *(const float4*)&Zs[grow][jq*8 + 4];
    float4 bvA = *(const float4*)&bias_s[jq*8];
    float4 bvB = *(const float4*)&bias_s[jq*8 + 4];
    float zi0 = z0.x + bvA.x, zf0 = z0.y + bvA.y, zg0 = z0.z + bvA.z, zo0 = z0.w + bvA.w;
    float zi1 = z1.x + bvB.x, zf1 = z1.y + bvB.y, zg1 = z1.z + bvB.z, zo1 = z1.w + bvB.w;
    float c0 = sigf(zf0)*creg.x + sigf(zi0)*tanh_(zg0);
    float c1 = sigf(zf1)*creg.y + sigf(zi1)*tanh_(zg1);
    creg.x = c0; creg.y = c1;
    float h0 = sigf(zo0)*tanh_(c0);
    float h1 = sigf(zo1)*tanh_(c1);
    unsigned short hh0 = f2bf(h0), hh1 = f2bf(h1);
    unsigned short hl0 = f2bf(h0 - bf2f(hh0)), hl1 = f2bf(h1 - bf2f(hh1));
    if (fast) {
      // plain stores: land dirty in the XCD-local L2 (the group's h home)
      *(ushort2*)&hout[hwbase]       = make_ushort2(hh0, hh1);
      *(ushort2*)&hout[hwbase + 512] = make_ushort2(hl0, hl1);
    } else {
      unsigned hip = (unsigned)hh0 | ((unsigned)hh1 << 16);
      unsigned lop = (unsigned)hl0 | ((unsigned)hl1 << 16);
      asm volatile("global_store_dword %0, %1, off sc0 sc1"
                   :: "v"(hout + hwbase), "v"(hip) : "memory");
      asm volatile("global_store_dword %0, %1, off sc0 sc1"
                   :: "v"(hout + hwbase + 512), "v"(lop) : "memory");
    }
  }

  if (!WARM && tid < 64) {
    float sum = red[0][tid] + red[1][tid] + red[2][tid] + red[3][tid] + bdc;
    out[((size_t)(g*64 + tid)*NSQ + s_out)*NO + cb] = sum;
  }
}

// ---------------- persistent fused LSTM (runtime XCD-verified grouping) ------
// Phase 0: every block reads its physical XCD (s_getreg XCC_ID, m09) and takes
// rank = atomicAdd(cnt[xcd]). If all 8 XCDs have exactly 32 blocks -> FAST mode:
// role (g,cb) = (xcd, rank); group h traffic stays in the XCD-local L2 (plain
// stores + sc0 loads). Else -> SLOW mode: roles = blockIdx split, full coherent
// path (exact R7 behavior, proven correct). Mode is uniform across blocks.
__global__ __launch_bounds__(512, 2)
void lstm_persist_k(ushort_t* __restrict__ hA, ushort_t* __restrict__ hB,
                    const ushort_t* __restrict__ Wpk, const ushort_t* __restrict__ Wppk,
                    const ushort_t* __restrict__ Wxpk, const ushort_t* __restrict__ xpk,
                    const float* __restrict__ b_p, const float* __restrict__ bp_p,
                    const float* __restrict__ WdT, const float* __restrict__ bd,
                    unsigned* __restrict__ flags, float* __restrict__ out)
{
  __shared__ float Zs[64][68];
  __shared__ float wdcol[512];
  __shared__ float red[4][64];
  __shared__ float bias_s[64];
  __shared__ unsigned sh_role;   // fast<<16 | g<<8 | cb

  const int tid = threadIdx.x;
  const int lane = tid & 63;
  const int wv = tid >> 6;
  const int wr = wv & 1, kq = wv >> 1;

  // ---- phase 0: runtime XCD discovery + balance check ----
  unsigned* cnt = flags + 256;   // cnt[0..7]=per-XCD, cnt[8]=arrivals (zeroed)
  if (tid == 0) {
    unsigned xcd;
    asm volatile("s_getreg_b32 %0, hwreg(HW_REG_XCC_ID)" : "=s"(xcd));
    xcd &= 7u;
    unsigned rank = __hip_atomic_fetch_add(&cnt[xcd], 1u, __ATOMIC_RELAXED,
                                           __HIP_MEMORY_SCOPE_AGENT);
    __hip_atomic_fetch_add(&cnt[8], 1u, __ATOMIC_RELEASE, __HIP_MEMORY_SCOPE_AGENT);
    while (__hip_atomic_load(&cnt[8], __ATOMIC_ACQUIRE, __HIP_MEMORY_SCOPE_AGENT) < 256u)
      __builtin_amdgcn_s_sleep(2);
    bool bal = true;
    #pragma unroll
    for (int i = 0; i < 8; ++i)
      bal = bal && (__hip_atomic_load(&cnt[i], __ATOMIC_RELAXED,
                                      __HIP_MEMORY_SCOPE_AGENT) == 32u);
    unsigned g_, cb_;
    if (bal) { g_ = xcd; cb_ = rank; }
    else     { g_ = (unsigned)blockIdx.x & 7u; cb_ = (unsigned)blockIdx.x >> 3; }
    sh_role = ((unsigned)bal << 16) | (g_ << 8) | cb_;
  }
  __syncthreads();
  const int fast = (int)(sh_role >> 16);
  const int g  = (int)((sh_role >> 8) & 255u);
  const int cb = (int)(sh_role & 255u);

  unsigned* gflags = flags + g*32;

  const int grow = tid >> 3;
  const int jq = tid & 7;
  const int lane_w = (grow & 31) + 32*(jq >> 2);
  const int e0 = (jq*2) & 7;
  const size_t hwbase = (((size_t)(g*2 + (grow>>5))*32 + cb)*2)*512 + lane_w*8 + e0;
  const size_t Ab = (((size_t)(g*2 + wr)*32 + kq*8)*2)*512 + lane*8;

  // persistent weight panel (warmup set)
  bf16x8 bh0[8], bl0[8], bh1[8], bl1[8];
  {
    const ushort_t* Wsec = Wpk + (size_t)cb*65536;
    #pragma unroll
    for (int s = 0; s < 8; ++s) {
      const ushort_t* p = Wsec + (size_t)(kq*8+s)*2048 + lane*8;
      bh0[s] = vload16(p);        bl0[s] = vload16(p + 512);
      bh1[s] = vload16(p + 1024); bl1[s] = vload16(p + 1536);
    }
  }
  const ushort_t* wxp = Wxpk + (size_t)(cb*2 + (kq>>1))*2048 + lane*8;

  wdcol[tid] = WdT[(size_t)cb*512 + tid];
  if (tid < 64) bias_s[tid] = b_p[cb*64 + tid];
  const float bdc = bd[cb];
  float2 creg = make_float2(0.f, 0.f);
  __syncthreads();

  // ---- warmup: 64 steps with x ----
  for (int t = 0; t < 64; ++t) {
    const ushort_t* hin = (t & 1) ? hB : hA;
    ushort_t* hout = (t & 1) ? hA : hB;
    const ushort_t* xp = xpk + ((((size_t)t*8 + g)*2 + wr)*2 + (kq>>1))*1024 + lane*8;
    lstm_step<true>(hin, hout, bh0, bl0, bh1, bl1, wxp, xp,
                    Zs, wdcol, red, bias_s, creg, fast,
                    tid, lane, wr, kq, g, cb, Ab, hwbase, out, 0, bdc);
    gridbar(gflags, cb, (unsigned)(t+1), wv, lane);
  }

  // ---- switch to folded decode weights + folded bias ----
  {
    const ushort_t* Wsec = Wppk + (size_t)cb*65536;
    #pragma unroll
    for (int s = 0; s < 8; ++s) {
      const ushort_t* p = Wsec + (size_t)(kq*8+s)*2048 + lane*8;
      bh0[s] = vload16(p);        bl0[s] = vload16(p + 512);
      bh1[s] = vload16(p + 1024); bl1[s] = vload16(p + 1536);
    }
  }
  if (tid < 64) bias_s[tid] = bp_p[cb*64 + tid];
  __syncthreads();

  // ---- decode: 63 steps, step st emits pred_{st-64} from h_in ----
  for (int st = 64; st < 127; ++st) {
    const ushort_t* hin = (st & 1) ? hB : hA;
    ushort_t* hout = (st & 1) ? hA : hB;
    lstm_step<false>(hin, hout, bh0, bl0, bh1, bl1, wxp, hin /*unused*/,
                     Zs, wdcol, red, bias_s, creg, fast,
                     tid, lane, wr, kq, g, cb, Ab, hwbase, out, st - 64, bdc);
    gridbar(gflags, cb, (unsigned)(st+1), wv, lane);
  }

  // ---- final pred_63 from h'_63 (in hB) ----
  {
    const ushort_t* A0 = hB + Ab;
    uiv4 vh[8], vl[8];
    if (fast) {
      #pragma unroll
      for (int s = 0; s < 8; ++s) {
        asm volatile("global_load_dwordx4 %0, %1, off sc0"
                     : "=v"(vh[s]) : "v"(A0 + (size_t)s*1024) : "memory");
        asm volatile("global_load_dwordx4 %0, %1, off sc0"
                     : "=v"(vl[s]) : "v"(A0 + (size_t)s*1024 + 512) : "memory");
      }
    } else {
      #pragma unroll
      for (int s = 0; s < 8; ++s) {
        asm volatile("global_load_dwordx4 %0, %1, off sc0 sc1"
                     : "=v"(vh[s]) : "v"(A0 + (size_t)s*1024) : "memory");
        asm volatile("global_load_dwordx4 %0, %1, off sc0 sc1"
                     : "=v"(vl[s]) : "v"(A0 + (size_t)s*1024 + 512) : "memory");
      }
    }
    asm volatile("s_waitcnt vmcnt(0)" ::: "memory");
    __builtin_amdgcn_sched_barrier(0);
    const int kwb = kq*128 + (lane>>5)*8;
    float pacc = 0.f;
    #pragma unroll
    for (int s = 0; s < 8; ++s) {
      const bf16x8 a_h = as_bf(vh[s]);
      const bf16x8 a_l = as_bf(vl[s]);
      float4 w0 = *(const float4*)&wdcol[kwb + s*16];
      float4 w1 = *(const float4*)&wdcol[kwb + s*16 + 4];
      pacc += (bf2f_s(a_h[0])+bf2f_s(a_l[0]))*w0.x + (bf2f_s(a_h[1])+bf2f_s(a_l[1]))*w0.y
            + (bf2f_s(a_h[2])+bf2f_s(a_l[2]))*w0.z + (bf2f_s(a_h[3])+bf2f_s(a_l[3]))*w0.w;
      pacc += (bf2f_s(a_h[4])+bf2f_s(a_l[4]))*w1.x + (bf2f_s(a_h[5])+bf2f_s(a_l[5]))*w1.y
            + (bf2f_s(a_h[6])+bf2f_s(a_l[6]))*w1.z + (bf2f_s(a_h[7])+bf2f_s(a_l[7]))*w1.w;
    }
    pacc += __shfl_xor(pacc, 32);
    if (lane < 32) red[kq][wr*32 + lane] = pacc;
    __syncthreads();
    if (tid < 64) {
      float sum = red[0][tid] + red[1][tid] + red[2][tid] + red[3][tid] + bdc;
      out[((size_t)(g*64 + tid)*NSQ + 63)*NO + cb] = sum;
    }
  }
}

extern "C" void kernel_launch(void* const* d_in, const int* in_sizes, int n_in,
                              void* d_out, int out_size, void* d_ws, size_t ws_size,
                              hipStream_t stream) {
  (void)in_sizes; (void)n_in; (void)out_size; (void)ws_size;
  const float* x  = (const float*)d_in[0];   // (512, 64, 32)
  const float* Wx = (const float*)d_in[1];   // (32, 2048)
  const float* Wh = (const float*)d_in[2];   // (512, 2048)
  const float* b  = (const float*)d_in[3];   // (2048,)
  const float* Wd = (const float*)d_in[4];   // (512, 32)
  const float* bd = (const float*)d_in[5];   // (32,)
  float* out = (float*)d_out;                // (512, 64, 32)

  // ws layout, ~15.0 MB total
  char* w = (char*)d_ws;
  ushort_t* hA    = (ushort_t*)(w + 0);            // 1 MB  (zeroed)
  unsigned* flags = (unsigned*)(w + 1048576);      // flags[256] + cnt[9] (zeroed)
  ushort_t* hB    = (ushort_t*)(w + 1052672);      // 1 MB
  ushort_t* Wpk   = (ushort_t*)(w + 2101248);      // 4 MB
  ushort_t* Wppk  = (ushort_t*)(w + 6295552);      // 4 MB
  ushort_t* Wxpk  = (ushort_t*)(w + 10489856);     // 256 KB
  ushort_t* xpk   = (ushort_t*)(w + 10752000);     // 4 MB
  float* b_p  = (float*)(w + 14946304);            // 8 KB
  float* bp_p = (float*)(w + 14954496);            // 8 KB
  float* WdT  = (float*)(w + 14962688);            // 64 KB

  zero_k<<<257, 256, 0, stream>>>((float4*)w, 65792);   // hA + flags + cnt
  prep_w_k<<<1024, 256, 0, stream>>>(Wh, Wd, Wx, Wpk, Wppk);
  prep_wx_k<<<64, 256, 0, stream>>>(Wx, Wxpk);
  prep_x_k<<<1024, 256, 0, stream>>>(x, xpk);
  prep_bias_k<<<8, 256, 0, stream>>>(b, bd, Wx, b_p, bp_p);
  prep_wd_k<<<64, 256, 0, stream>>>(Wd, WdT);

  lstm_persist_k<<<256, 512, 0, stream>>>(hA, hB, Wpk, Wppk, Wxpk, xpk,
                                          b_p, bp_p, WdT, bd, flags, out);
}